// Round 20
// baseline (154.714 us; speedup 1.0000x reference)
//
#include <hip/hip_runtime.h>
#include <hip/hip_bf16.h>
#include <stdint.h>

#define NTOK 49
#define DIM  128
#define NH   4
#define QKVN 384
#define SCALE 0.17677669529663687f
#define LOG2E 1.4426950408889634f

typedef __bf16 bfloat_t;
typedef bfloat_t bf16x8 __attribute__((ext_vector_type(8)));
typedef bfloat_t bf16x4 __attribute__((ext_vector_type(4)));
typedef short    s16x4  __attribute__((ext_vector_type(4)));
typedef float    f32x4  __attribute__((ext_vector_type(4)));

#define MFMA32(a, b, c) __builtin_amdgcn_mfma_f32_16x16x32_bf16(a, b, c, 0, 0, 0)
#define MFMA16(a, b, c) __builtin_amdgcn_mfma_f32_16x16x16bf16_1k(a, b, c, 0, 0, 0)

static __device__ __forceinline__ bf16x4 pk4(f32x4 a) {
    bf16x4 r = { (bfloat_t)a[0], (bfloat_t)a[1], (bfloat_t)a[2], (bfloat_t)a[3] };
    return r;
}
static __device__ __forceinline__ s16x4 asi(bf16x4 v) {
    return __builtin_bit_cast(s16x4, v);
}

// Wq rows pre-scaled by SCALE*LOG2E so QK^T logits arrive in base-2 scale
// (kernel then uses raw v_exp_f32 via exp2 with no per-element mul).
__global__ void prep_weights(const float* __restrict__ qkvw,
                             const float* __restrict__ projw,
                             bfloat_t* __restrict__ qkvw_b,
                             bfloat_t* __restrict__ projw_b) {
    int i = blockIdx.x * 256 + threadIdx.x;
    if (i < QKVN * DIM) {
        float s = (i < 128 * DIM) ? (SCALE * LOG2E) : 1.f;
        qkvw_b[i] = (bfloat_t)(qkvw[i] * s);
    }
    if (i < DIM * DIM)  projw_b[i] = (bfloat_t)projw[i];
}

// cmb[w][h][tok_q][tok_k] = (bias + mask) * LOG2E; tok_k>=49 -> -1e30*LOG2E
// (exp2 -> 0 exactly); tok_q>=49 -> 0
__global__ void prep_cmb(const float* __restrict__ mask,
                         const float* __restrict__ bias_table,
                         const int* __restrict__ rel_index,
                         float* __restrict__ cmb) {
    int wh = blockIdx.x;            // w*NH + h
    int w = wh >> 2, h = wh & 3;
    for (int idx = threadIdx.x; idx < 4096; idx += 256) {
        int row = idx >> 6, col = idx & 63;   // row=tok_q, col=tok_k
        float v;
        if (col >= NTOK)      v = -1e30f;
        else if (row >= NTOK) v = 0.f;
        else v = bias_table[rel_index[row * NTOK + col] * NH + h]
               + mask[(w * NTOK + row) * NTOK + col];
        cmb[(size_t)wh * 4096 + idx] = v * LOG2E;
    }
}

// R20 = R13 (130.4us best) with SCALE+LOG2E folded into prep kernels:
// q-phase SCALE muls removed (bias scaled once at init), softmax uses raw
// __builtin_amdgcn_exp2f (v_exp_f32, no log2e mul) -- ~96 VALU ops off the
// hot path per wave; dependence-graph SHAPE identical to R13 (R19's lesson:
// shape changes re-roll the regalloc dice; pure-mul deletions do not add
// liveness). Guard: WRITE_SIZE == 100352 KB exactly; if dur >= 130.4, R13
// is the settled final.
// launch_bounds(256,3); LDS 32KB (x [0,16K) swz / ao [16K,32K)); 2 barriers.
__global__ __launch_bounds__(256, 3)
void win_attn(const float* __restrict__ x,
              const float* __restrict__ qkv_b,
              const float* __restrict__ proj_b,
              const bfloat_t* __restrict__ qkvw,
              const bfloat_t* __restrict__ projw,
              const float* __restrict__ cmb,
              float* __restrict__ out, int nw) {
    __shared__ __align__(16) char smem[32768];
    char* aosm = smem + 16384;
    const int b    = blockIdx.x;
    const int tid  = threadIdx.x;
    const int wave = tid >> 6;
    const int lane = tid & 63;
    const int g = lane >> 4;
    const int c = lane & 15;
    const int h = wave;

    // ---- stage x -> LDS bf16 [64 tok][128 d], 16B-granule XOR swizzle ----
    {
        const float* xb = x + (size_t)b * (NTOK * DIM);
        #pragma unroll
        for (int i = 0; i < 8; ++i) {
            const int s = tid + i * 256;            // 0..2047 b64 slots
            const int row = s >> 5, col4 = (s & 31) * 4;
            f32x4 v = (row < NTOK) ? *(const f32x4*)(xb + row * DIM + col4)
                                   : (f32x4){0.f, 0.f, 0.f, 0.f};
            *(bf16x4*)(smem + row * 256 + ((col4 * 2) ^ ((row & 7) << 4))) = pk4(v);
        }
    }
    __syncthreads();

    // x A-frag (K=32): [tok=t*16+c][d = ks*32 + g*8 .. +7]
    #define LDX(t, ks) (*(const bf16x8*)(smem + ((t)*16 + c) * 256 + \
                        (((ks)*64 + g*16) ^ ((c & 7) << 4))))

    bf16x4 qp[2][4], kp[2][4], vp[4][2];   // packed frags, chunk layout = C/D layout

    // ---- q^T = Wq_h . x^T (Wq pre-scaled; bias scaled once at init) ----
    {
        f32x4 acc[2][4];
        #pragma unroll
        for (int mtd = 0; mtd < 2; ++mtd) {
            f32x4 qb4 = *(const f32x4*)(qkv_b + h * 32 + mtd * 16 + g * 4);
            #pragma unroll
            for (int r = 0; r < 4; ++r) qb4[r] *= (SCALE * LOG2E);
            #pragma unroll
            for (int nt = 0; nt < 4; ++nt) acc[mtd][nt] = qb4;
        }
        #pragma unroll
        for (int ks = 0; ks < 4; ++ks) {
            bf16x8 w0 = *(const bf16x8*)(qkvw + (h * 32 +  0 + c) * DIM + ks * 32 + g * 8);
            bf16x8 w1 = *(const bf16x8*)(qkvw + (h * 32 + 16 + c) * DIM + ks * 32 + g * 8);
            #pragma unroll
            for (int nt = 0; nt < 4; ++nt) {
                bf16x8 a = LDX(nt, ks);
                acc[0][nt] = MFMA32(w0, a, acc[0][nt]);
                acc[1][nt] = MFMA32(w1, a, acc[1][nt]);
            }
        }
        #pragma unroll
        for (int ds = 0; ds < 2; ++ds)
            #pragma unroll
            for (int nt = 0; nt < 4; ++nt) qp[ds][nt] = pk4(acc[ds][nt]);
    }

    // ---- k^T = Wk_h . x^T ----
    {
        f32x4 acc[2][4];
        #pragma unroll
        for (int mtd = 0; mtd < 2; ++mtd) {
            const f32x4 kb4 = *(const f32x4*)(qkv_b + DIM + h * 32 + mtd * 16 + g * 4);
            #pragma unroll
            for (int nt = 0; nt < 4; ++nt) acc[mtd][nt] = kb4;
        }
        #pragma unroll
        for (int ks = 0; ks < 4; ++ks) {
            bf16x8 w0 = *(const bf16x8*)(qkvw + (DIM + h * 32 +  0 + c) * DIM + ks * 32 + g * 8);
            bf16x8 w1 = *(const bf16x8*)(qkvw + (DIM + h * 32 + 16 + c) * DIM + ks * 32 + g * 8);
            #pragma unroll
            for (int nt = 0; nt < 4; ++nt) {
                bf16x8 a = LDX(nt, ks);
                acc[0][nt] = MFMA32(w0, a, acc[0][nt]);
                acc[1][nt] = MFMA32(w1, a, acc[1][nt]);
            }
        }
        #pragma unroll
        for (int ds = 0; ds < 2; ++ds)
            #pragma unroll
            for (int nt = 0; nt < 4; ++nt) kp[ds][nt] = pk4(acc[ds][nt]);
    }

    // ---- v = x . Wv_h^T : D[m=tok(4 tiles)][n=d(2 tiles)] ----
    {
        f32x4 acc[4][2];
        #pragma unroll
        for (int nt = 0; nt < 2; ++nt) {
            const float vb = qkv_b[2 * DIM + h * 32 + nt * 16 + c];
            #pragma unroll
            for (int mt = 0; mt < 4; ++mt) acc[mt][nt] = (f32x4){vb, vb, vb, vb};
        }
        #pragma unroll
        for (int ks = 0; ks < 4; ++ks) {
            bf16x8 w0 = *(const bf16x8*)(qkvw + (2 * DIM + h * 32 +  0 + c) * DIM + ks * 32 + g * 8);
            bf16x8 w1 = *(const bf16x8*)(qkvw + (2 * DIM + h * 32 + 16 + c) * DIM + ks * 32 + g * 8);
            #pragma unroll
            for (int mt = 0; mt < 4; ++mt) {
                bf16x8 a = LDX(mt, ks);
                acc[mt][0] = MFMA32(a, w0, acc[mt][0]);
                acc[mt][1] = MFMA32(a, w1, acc[mt][1]);
            }
        }
        #pragma unroll
        for (int mt = 0; mt < 4; ++mt)
            #pragma unroll
            for (int nt = 0; nt < 2; ++nt) vp[mt][nt] = pk4(acc[mt][nt]);
    }

    // ---- fused per-ntq: S^T tile (cmb C-init, base-2 scale) -> softmax -> PV ----
    {
        const float* cw = cmb + (size_t)((b % nw) * NH + h) * 4096;
        #pragma unroll
        for (int ntq = 0; ntq < 4; ++ntq) {
            f32x4 s[4];
            #pragma unroll
            for (int mtk = 0; mtk < 4; ++mtk)
                s[mtk] = *(const f32x4*)(cw + (ntq * 16 + c) * 64 + mtk * 16 + g * 4);
            #pragma unroll
            for (int mtk = 0; mtk < 4; ++mtk) {
                s[mtk] = MFMA16(asi(kp[0][mtk]), asi(qp[0][ntq]), s[mtk]);
                s[mtk] = MFMA16(asi(kp[1][mtk]), asi(qp[1][ntq]), s[mtk]);
            }
            // tree max (depth ~6)
            f32x4 t01, t23;
            #pragma unroll
            for (int r = 0; r < 4; ++r) {
                t01[r] = fmaxf(s[0][r], s[1][r]);
                t23[r] = fmaxf(s[2][r], s[3][r]);
            }
            #pragma unroll
            for (int r = 0; r < 4; ++r) t01[r] = fmaxf(t01[r], t23[r]);
            float m = fmaxf(fmaxf(t01[0], t01[1]), fmaxf(t01[2], t01[3]));
            m = fmaxf(m, __shfl_xor(m, 16));
            m = fmaxf(m, __shfl_xor(m, 32));
            // exp2 (raw v_exp_f32 -- logits already base-2 scaled) + tree sum
            #pragma unroll
            for (int mtk = 0; mtk < 4; ++mtk)
                #pragma unroll
                for (int r = 0; r < 4; ++r)
                    s[mtk][r] = __builtin_amdgcn_exp2f(s[mtk][r] - m);
            f32x4 u01, u23;
            #pragma unroll
            for (int r = 0; r < 4; ++r) {
                u01[r] = s[0][r] + s[1][r];
                u23[r] = s[2][r] + s[3][r];
            }
            #pragma unroll
            for (int r = 0; r < 4; ++r) u01[r] += u23[r];
            float sum = (u01[0] + u01[1]) + (u01[2] + u01[3]);
            sum += __shfl_xor(sum, 16);
            sum += __shfl_xor(sum, 32);
            const float dinv = 1.f / sum;

            bf16x4 pa[4];
            #pragma unroll
            for (int mtk = 0; mtk < 4; ++mtk) pa[mtk] = pk4(s[mtk]);

            // PV as 2x2 partial chains (4 independent dependent-MFMA chains)
            f32x4 o0a = {0.f,0.f,0.f,0.f}, o0b = {0.f,0.f,0.f,0.f};
            f32x4 o1a = {0.f,0.f,0.f,0.f}, o1b = {0.f,0.f,0.f,0.f};
            o0a = MFMA16(asi(vp[0][0]), asi(pa[0]), o0a);
            o0b = MFMA16(asi(vp[2][0]), asi(pa[2]), o0b);
            o1a = MFMA16(asi(vp[0][1]), asi(pa[0]), o1a);
            o1b = MFMA16(asi(vp[2][1]), asi(pa[2]), o1b);
            o0a = MFMA16(asi(vp[1][0]), asi(pa[1]), o0a);
            o0b = MFMA16(asi(vp[3][0]), asi(pa[3]), o0b);
            o1a = MFMA16(asi(vp[1][1]), asi(pa[1]), o1a);
            o1b = MFMA16(asi(vp[3][1]), asi(pa[3]), o1b);
            f32x4 so0 = { (o0a[0]+o0b[0])*dinv, (o0a[1]+o0b[1])*dinv,
                          (o0a[2]+o0b[2])*dinv, (o0a[3]+o0b[3])*dinv };
            f32x4 so1 = { (o1a[0]+o1b[0])*dinv, (o1a[1]+o1b[1])*dinv,
                          (o1a[2]+o1b[2])*dinv, (o1a[3]+o1b[3])*dinv };
            // ao[tok][d] bf16, 16B-granule swizzle ^ (c&15); mtd = 0 and 1
            const int base = (ntq*16 + c)*256 + ((g&1) << 3);
            *(bf16x4*)(aosm + base + ((((h*4 + 0 + (g>>1)) ^ c) & 15) << 4)) = pk4(so0);
            *(bf16x4*)(aosm + base + ((((h*4 + 2 + (g>>1)) ^ c) & 15) << 4)) = pk4(so1);
        }
    }
    __syncthreads();   // ao writes complete (x region untouched; no overlay)

    // ---- out^T = Wp . ao^T : wave owns 32 output cols; f32x4 stores ----
    {
        f32x4 po[2][4];
        #pragma unroll
        for (int mtO = 0; mtO < 2; ++mtO) {
            const f32x4 pb4 = *(const f32x4*)(proj_b + wave * 32 + mtO * 16 + g * 4);
            #pragma unroll
            for (int nt = 0; nt < 4; ++nt) po[mtO][nt] = pb4;
        }
        #pragma unroll
        for (int ks = 0; ks < 4; ++ks) {
            bf16x8 w0 = *(const bf16x8*)(projw + (wave * 32 +  0 + c) * DIM + ks * 32 + g * 8);
            bf16x8 w1 = *(const bf16x8*)(projw + (wave * 32 + 16 + c) * DIM + ks * 32 + g * 8);
            bf16x8 aof[4];
            #pragma unroll
            for (int nt = 0; nt < 4; ++nt)
                aof[nt] = *(const bf16x8*)(aosm + (nt*16 + c)*256 + ((((ks*4 + g) ^ c) & 15) << 4));
            #pragma unroll
            for (int nt = 0; nt < 4; ++nt) {
                po[0][nt] = MFMA32(w0, aof[nt], po[0][nt]);
                po[1][nt] = MFMA32(w1, aof[nt], po[1][nt]);
            }
        }
        float* og = out + (size_t)b * (NTOK * DIM);
        #pragma unroll
        for (int nt = 0; nt < 4; ++nt) {
            const int tok = nt * 16 + c;
            if (tok < NTOK) {
                #pragma unroll
                for (int mtO = 0; mtO < 2; ++mtO)
                    *(f32x4*)(og + tok * DIM + wave * 32 + mtO * 16 + g * 4) = po[mtO][nt];
            }
        }
    }
    #undef LDX
}

extern "C" void kernel_launch(void* const* d_in, const int* in_sizes, int n_in,
                              void* d_out, int out_size, void* d_ws, size_t ws_size,
                              hipStream_t stream) {
    (void)n_in; (void)out_size; (void)ws_size;
    const float* x          = (const float*)d_in[0];
    const float* mask       = (const float*)d_in[1];
    const float* qkv_w      = (const float*)d_in[2];
    const float* qkv_b      = (const float*)d_in[3];
    const float* proj_w     = (const float*)d_in[4];
    const float* proj_b     = (const float*)d_in[5];
    const float* bias_table = (const float*)d_in[6];
    const int*   rel_index  = (const int*)d_in[7];
    float* out = (float*)d_out;

    char* ws = (char*)d_ws;
    bfloat_t* qkvw_b  = (bfloat_t*)ws;              // 98304 B
    bfloat_t* projw_b = (bfloat_t*)(ws + 98304);    // 32768 B
    float*    cmb     = (float*)(ws + 131072);      // nw*NH*64*64*4 B

    const int B  = in_sizes[0] / (NTOK * DIM);
    const int nw = in_sizes[1] / (NTOK * NTOK);

    prep_weights<<<dim3((QKVN * DIM + 255) / 256), dim3(256), 0, stream>>>(qkv_w, proj_w, qkvw_b, projw_b);
    prep_cmb<<<dim3(nw * NH), dim3(256), 0, stream>>>(mask, bias_table, rel_index, cmb);
    win_attn<<<dim3(B), dim3(256), 0, stream>>>(x, qkv_b, proj_b, qkvw_b, projw_b, cmb, out, nw);
}

// Round 21
// 130.082 us; speedup vs baseline: 1.1894x; 1.1894x over previous
//
#include <hip/hip_runtime.h>
#include <hip/hip_bf16.h>
#include <stdint.h>

#define NTOK 49
#define DIM  128
#define NH   4
#define QKVN 384
#define SCALE 0.17677669529663687f

typedef __bf16 bfloat_t;
typedef bfloat_t bf16x8 __attribute__((ext_vector_type(8)));
typedef bfloat_t bf16x4 __attribute__((ext_vector_type(4)));
typedef short    s16x4  __attribute__((ext_vector_type(4)));
typedef float    f32x4  __attribute__((ext_vector_type(4)));

#define MFMA32(a, b, c) __builtin_amdgcn_mfma_f32_16x16x32_bf16(a, b, c, 0, 0, 0)
#define MFMA16(a, b, c) __builtin_amdgcn_mfma_f32_16x16x16bf16_1k(a, b, c, 0, 0, 0)

static __device__ __forceinline__ bf16x4 pk4(f32x4 a) {
    bf16x4 r = { (bfloat_t)a[0], (bfloat_t)a[1], (bfloat_t)a[2], (bfloat_t)a[3] };
    return r;
}
static __device__ __forceinline__ s16x4 asi(bf16x4 v) {
    return __builtin_bit_cast(s16x4, v);
}

__global__ void prep_weights(const float* __restrict__ qkvw,
                             const float* __restrict__ projw,
                             bfloat_t* __restrict__ qkvw_b,
                             bfloat_t* __restrict__ projw_b) {
    int i = blockIdx.x * 256 + threadIdx.x;
    if (i < QKVN * DIM) qkvw_b[i] = (bfloat_t)qkvw[i];
    if (i < DIM * DIM)  projw_b[i] = (bfloat_t)projw[i];
}

// cmb[w][h][tok_q(64)][tok_k(64)] = bias + mask; tok_k>=49 -> -1e30; tok_q>=49 -> 0
__global__ void prep_cmb(const float* __restrict__ mask,
                         const float* __restrict__ bias_table,
                         const int* __restrict__ rel_index,
                         float* __restrict__ cmb) {
    int wh = blockIdx.x;            // w*NH + h
    int w = wh >> 2, h = wh & 3;
    for (int idx = threadIdx.x; idx < 4096; idx += 256) {
        int row = idx >> 6, col = idx & 63;   // row=tok_q, col=tok_k
        float v;
        if (col >= NTOK)      v = -1e30f;
        else if (row >= NTOK) v = 0.f;
        else v = bias_table[rel_index[row * NTOK + col] * NH + h]
               + mask[(w * NTOK + row) * NTOK + col];
        cmb[(size_t)wh * 4096 + idx] = v;
    }
}

// ===== FINAL == R13 (session best: 130.4us, WRITE==output, no spill) ========
// One block = one window; wave = head. Register-chained MFMA pipeline
// (16x16x16 C/D layout == A/B operand layout). S+softmax+PV fused per tok_q
// tile; O streamed to the ao LDS region (no op array). launch_bounds(256,3):
// ~168 unified regs/wave is the knife edge -- every perturbation (R12
// prefetch, R14 merged-QK, R15 setprio, R16 cadd split, R17 grid-stride,
// R19 no-max, R20 exp2-fold) either spilled (WRITE 125-714MB vs 100MB
// output) or was null; occupancy>3blk needs arch<=64 regs and spills.
// Latency-bound local optimum: MfmaUtil ~14, VALU ~21, HBM ~5%, occ ~31%.
// LDS 32KB: x tile [0,16K) swizzled; ao exchange [16K,32K). 2 barriers.
__global__ __launch_bounds__(256, 3)
void win_attn(const float* __restrict__ x,
              const float* __restrict__ qkv_b,
              const float* __restrict__ proj_b,
              const bfloat_t* __restrict__ qkvw,
              const bfloat_t* __restrict__ projw,
              const float* __restrict__ cmb,
              float* __restrict__ out, int nw) {
    __shared__ __align__(16) char smem[32768];
    char* aosm = smem + 16384;
    const int b    = blockIdx.x;
    const int tid  = threadIdx.x;
    const int wave = tid >> 6;
    const int lane = tid & 63;
    const int g = lane >> 4;
    const int c = lane & 15;
    const int h = wave;

    // ---- stage x -> LDS bf16 [64 tok][128 d], 16B-granule XOR swizzle ----
    {
        const float* xb = x + (size_t)b * (NTOK * DIM);
        #pragma unroll
        for (int i = 0; i < 8; ++i) {
            const int s = tid + i * 256;            // 0..2047 b64 slots
            const int row = s >> 5, col4 = (s & 31) * 4;
            f32x4 v = (row < NTOK) ? *(const f32x4*)(xb + row * DIM + col4)
                                   : (f32x4){0.f, 0.f, 0.f, 0.f};
            *(bf16x4*)(smem + row * 256 + ((col4 * 2) ^ ((row & 7) << 4))) = pk4(v);
        }
    }
    __syncthreads();

    // x A-frag (K=32): [tok=t*16+c][d = ks*32 + g*8 .. +7]
    #define LDX(t, ks) (*(const bf16x8*)(smem + ((t)*16 + c) * 256 + \
                        (((ks)*64 + g*16) ^ ((c & 7) << 4))))

    bf16x4 qp[2][4], kp[2][4], vp[4][2];   // packed frags, chunk layout = C/D layout

    // ---- q^T = Wq_h . x^T : D[m=d(2 tiles)][n=tok(4 tiles)] ----
    {
        f32x4 acc[2][4];
        #pragma unroll
        for (int mtd = 0; mtd < 2; ++mtd) {
            const f32x4 qb4 = *(const f32x4*)(qkv_b + h * 32 + mtd * 16 + g * 4);
            #pragma unroll
            for (int nt = 0; nt < 4; ++nt) acc[mtd][nt] = qb4;
        }
        #pragma unroll
        for (int ks = 0; ks < 4; ++ks) {
            bf16x8 w0 = *(const bf16x8*)(qkvw + (h * 32 +  0 + c) * DIM + ks * 32 + g * 8);
            bf16x8 w1 = *(const bf16x8*)(qkvw + (h * 32 + 16 + c) * DIM + ks * 32 + g * 8);
            #pragma unroll
            for (int nt = 0; nt < 4; ++nt) {
                bf16x8 a = LDX(nt, ks);
                acc[0][nt] = MFMA32(w0, a, acc[0][nt]);
                acc[1][nt] = MFMA32(w1, a, acc[1][nt]);
            }
        }
        #pragma unroll
        for (int ds = 0; ds < 2; ++ds)
            #pragma unroll
            for (int nt = 0; nt < 4; ++nt) {
                f32x4 a = acc[ds][nt];
                f32x4 sc = { a[0]*SCALE, a[1]*SCALE, a[2]*SCALE, a[3]*SCALE };
                qp[ds][nt] = pk4(sc);
            }
    }

    // ---- k^T = Wk_h . x^T ----
    {
        f32x4 acc[2][4];
        #pragma unroll
        for (int mtd = 0; mtd < 2; ++mtd) {
            const f32x4 kb4 = *(const f32x4*)(qkv_b + DIM + h * 32 + mtd * 16 + g * 4);
            #pragma unroll
            for (int nt = 0; nt < 4; ++nt) acc[mtd][nt] = kb4;
        }
        #pragma unroll
        for (int ks = 0; ks < 4; ++ks) {
            bf16x8 w0 = *(const bf16x8*)(qkvw + (DIM + h * 32 +  0 + c) * DIM + ks * 32 + g * 8);
            bf16x8 w1 = *(const bf16x8*)(qkvw + (DIM + h * 32 + 16 + c) * DIM + ks * 32 + g * 8);
            #pragma unroll
            for (int nt = 0; nt < 4; ++nt) {
                bf16x8 a = LDX(nt, ks);
                acc[0][nt] = MFMA32(w0, a, acc[0][nt]);
                acc[1][nt] = MFMA32(w1, a, acc[1][nt]);
            }
        }
        #pragma unroll
        for (int ds = 0; ds < 2; ++ds)
            #pragma unroll
            for (int nt = 0; nt < 4; ++nt) kp[ds][nt] = pk4(acc[ds][nt]);
    }

    // ---- v = x . Wv_h^T : D[m=tok(4 tiles)][n=d(2 tiles)] ----
    {
        f32x4 acc[4][2];
        #pragma unroll
        for (int nt = 0; nt < 2; ++nt) {
            const float vb = qkv_b[2 * DIM + h * 32 + nt * 16 + c];
            #pragma unroll
            for (int mt = 0; mt < 4; ++mt) acc[mt][nt] = (f32x4){vb, vb, vb, vb};
        }
        #pragma unroll
        for (int ks = 0; ks < 4; ++ks) {
            bf16x8 w0 = *(const bf16x8*)(qkvw + (2 * DIM + h * 32 +  0 + c) * DIM + ks * 32 + g * 8);
            bf16x8 w1 = *(const bf16x8*)(qkvw + (2 * DIM + h * 32 + 16 + c) * DIM + ks * 32 + g * 8);
            #pragma unroll
            for (int mt = 0; mt < 4; ++mt) {
                bf16x8 a = LDX(mt, ks);
                acc[mt][0] = MFMA32(a, w0, acc[mt][0]);
                acc[mt][1] = MFMA32(a, w1, acc[mt][1]);
            }
        }
        #pragma unroll
        for (int mt = 0; mt < 4; ++mt)
            #pragma unroll
            for (int nt = 0; nt < 2; ++nt) vp[mt][nt] = pk4(acc[mt][nt]);
    }

    // ---- fused per-ntq: S^T tile (cmb C-init) -> softmax -> PV -> ao LDS ----
    {
        const float* cw = cmb + (size_t)((b % nw) * NH + h) * 4096;
        #pragma unroll
        for (int ntq = 0; ntq < 4; ++ntq) {
            f32x4 s[4];
            #pragma unroll
            for (int mtk = 0; mtk < 4; ++mtk)
                s[mtk] = *(const f32x4*)(cw + (ntq * 16 + c) * 64 + mtk * 16 + g * 4);
            #pragma unroll
            for (int mtk = 0; mtk < 4; ++mtk) {
                s[mtk] = MFMA16(asi(kp[0][mtk]), asi(qp[0][ntq]), s[mtk]);
                s[mtk] = MFMA16(asi(kp[1][mtk]), asi(qp[1][ntq]), s[mtk]);
            }
            // tree max (depth ~6 instead of serial 15)
            f32x4 t01, t23;
            #pragma unroll
            for (int r = 0; r < 4; ++r) {
                t01[r] = fmaxf(s[0][r], s[1][r]);
                t23[r] = fmaxf(s[2][r], s[3][r]);
            }
            #pragma unroll
            for (int r = 0; r < 4; ++r) t01[r] = fmaxf(t01[r], t23[r]);
            float m = fmaxf(fmaxf(t01[0], t01[1]), fmaxf(t01[2], t01[3]));
            m = fmaxf(m, __shfl_xor(m, 16));
            m = fmaxf(m, __shfl_xor(m, 32));
            // exp (16 independent) + tree sum
            #pragma unroll
            for (int mtk = 0; mtk < 4; ++mtk)
                #pragma unroll
                for (int r = 0; r < 4; ++r) s[mtk][r] = __expf(s[mtk][r] - m);
            f32x4 u01, u23;
            #pragma unroll
            for (int r = 0; r < 4; ++r) {
                u01[r] = s[0][r] + s[1][r];
                u23[r] = s[2][r] + s[3][r];
            }
            #pragma unroll
            for (int r = 0; r < 4; ++r) u01[r] += u23[r];
            float sum = (u01[0] + u01[1]) + (u01[2] + u01[3]);
            sum += __shfl_xor(sum, 16);
            sum += __shfl_xor(sum, 32);
            const float dinv = 1.f / sum;

            bf16x4 pa[4];
            #pragma unroll
            for (int mtk = 0; mtk < 4; ++mtk) pa[mtk] = pk4(s[mtk]);

            // PV as 2x2 partial chains (4 independent dependent-MFMA chains)
            f32x4 o0a = {0.f,0.f,0.f,0.f}, o0b = {0.f,0.f,0.f,0.f};
            f32x4 o1a = {0.f,0.f,0.f,0.f}, o1b = {0.f,0.f,0.f,0.f};
            o0a = MFMA16(asi(vp[0][0]), asi(pa[0]), o0a);
            o0b = MFMA16(asi(vp[2][0]), asi(pa[2]), o0b);
            o1a = MFMA16(asi(vp[0][1]), asi(pa[0]), o1a);
            o1b = MFMA16(asi(vp[2][1]), asi(pa[2]), o1b);
            o0a = MFMA16(asi(vp[1][0]), asi(pa[1]), o0a);
            o0b = MFMA16(asi(vp[3][0]), asi(pa[3]), o0b);
            o1a = MFMA16(asi(vp[1][1]), asi(pa[1]), o1a);
            o1b = MFMA16(asi(vp[3][1]), asi(pa[3]), o1b);
            f32x4 so0 = { (o0a[0]+o0b[0])*dinv, (o0a[1]+o0b[1])*dinv,
                          (o0a[2]+o0b[2])*dinv, (o0a[3]+o0b[3])*dinv };
            f32x4 so1 = { (o1a[0]+o1b[0])*dinv, (o1a[1]+o1b[1])*dinv,
                          (o1a[2]+o1b[2])*dinv, (o1a[3]+o1b[3])*dinv };
            // ao[tok][d] bf16, 16B-granule swizzle ^ (c&15); mtd = 0 and 1
            const int base = (ntq*16 + c)*256 + ((g&1) << 3);
            *(bf16x4*)(aosm + base + ((((h*4 + 0 + (g>>1)) ^ c) & 15) << 4)) = pk4(so0);
            *(bf16x4*)(aosm + base + ((((h*4 + 2 + (g>>1)) ^ c) & 15) << 4)) = pk4(so1);
        }
    }
    __syncthreads();   // ao writes complete (x region untouched; no overlay)

    // ---- out^T = Wp . ao^T : wave owns 32 output cols; f32x4 stores ----
    {
        f32x4 po[2][4];
        #pragma unroll
        for (int mtO = 0; mtO < 2; ++mtO) {
            const f32x4 pb4 = *(const f32x4*)(proj_b + wave * 32 + mtO * 16 + g * 4);
            #pragma unroll
            for (int nt = 0; nt < 4; ++nt) po[mtO][nt] = pb4;
        }
        #pragma unroll
        for (int ks = 0; ks < 4; ++ks) {
            bf16x8 w0 = *(const bf16x8*)(projw + (wave * 32 +  0 + c) * DIM + ks * 32 + g * 8);
            bf16x8 w1 = *(const bf16x8*)(projw + (wave * 32 + 16 + c) * DIM + ks * 32 + g * 8);
            bf16x8 aof[4];
            #pragma unroll
            for (int nt = 0; nt < 4; ++nt)
                aof[nt] = *(const bf16x8*)(aosm + (nt*16 + c)*256 + ((((ks*4 + g) ^ c) & 15) << 4));
            #pragma unroll
            for (int nt = 0; nt < 4; ++nt) {
                po[0][nt] = MFMA32(w0, aof[nt], po[0][nt]);
                po[1][nt] = MFMA32(w1, aof[nt], po[1][nt]);
            }
        }
        float* og = out + (size_t)b * (NTOK * DIM);
        #pragma unroll
        for (int nt = 0; nt < 4; ++nt) {
            const int tok = nt * 16 + c;
            if (tok < NTOK) {
                #pragma unroll
                for (int mtO = 0; mtO < 2; ++mtO)
                    *(f32x4*)(og + tok * DIM + wave * 32 + mtO * 16 + g * 4) = po[mtO][nt];
            }
        }
    }
    #undef LDX
}

extern "C" void kernel_launch(void* const* d_in, const int* in_sizes, int n_in,
                              void* d_out, int out_size, void* d_ws, size_t ws_size,
                              hipStream_t stream) {
    (void)n_in; (void)out_size; (void)ws_size;
    const float* x          = (const float*)d_in[0];
    const float* mask       = (const float*)d_in[1];
    const float* qkv_w      = (const float*)d_in[2];
    const float* qkv_b      = (const float*)d_in[3];
    const float* proj_w     = (const float*)d_in[4];
    const float* proj_b     = (const float*)d_in[5];
    const float* bias_table = (const float*)d_in[6];
    const int*   rel_index  = (const int*)d_in[7];
    float* out = (float*)d_out;

    char* ws = (char*)d_ws;
    bfloat_t* qkvw_b  = (bfloat_t*)ws;              // 98304 B
    bfloat_t* projw_b = (bfloat_t*)(ws + 98304);    // 32768 B
    float*    cmb     = (float*)(ws + 131072);      // nw*NH*64*64*4 B

    const int B  = in_sizes[0] / (NTOK * DIM);
    const int nw = in_sizes[1] / (NTOK * NTOK);

    prep_weights<<<dim3((QKVN * DIM + 255) / 256), dim3(256), 0, stream>>>(qkv_w, proj_w, qkvw_b, projw_b);
    prep_cmb<<<dim3(nw * NH), dim3(256), 0, stream>>>(mask, bias_table, rel_index, cmb);
    win_attn<<<dim3(B), dim3(256), 0, stream>>>(x, qkv_b, proj_b, qkvw_b, projw_b, cmb, out, nw);
}